// Round 11
// baseline (653.855 us; speedup 1.0000x reference)
//
#include <hip/hip_runtime.h>
#include <math.h>

#define B_  8192
#define E_  8
#define D_  3072
#define H_  256
#define C_  100
#define DH_ (D_*H_)
#define HC_ (H_*C_)
#define KS_ 8            // K splits in gemm1
#define KSEG_ (D_/KS_)   // 384
#define RKS_ 16          // K splits in router
#define RSEG_ (D_/RKS_)  // 192
#define RB_ (B_/256)     // 32 row-blocks of 256 rows
#define NTMAX_ 136       // max 64-row tiles over all experts (128+8 slack)
#define NT2MAX_ 528      // max 16-row tiles (512+16 slack)
#define NCH_ (D_/32)     // 96 32-k chunks
#define CHW_ 10240       // ushorts per weight chunk block: 256 cols * 40

// mega-kernel block ranges (router first: it's on the critical path)
#define MEGA_R_   (RB_*RKS_)          // 512 router blocks (4 waves x 64 rows)
#define MEGA_W1_  (E_*NCH_)           // 768 W1 chunk tiles (1 block per (e,ci))
#define MEGA_W2_  (C_*E_)             // 800 blendw2t columns
#define MEGA_BB_  3                   // b1/b2 blend blocks
#define MEGA_TOT_ (MEGA_R_ + MEGA_W1_ + MEGA_W2_ + MEGA_BB_)

typedef __attribute__((ext_vector_type(4))) float  f32x4;
typedef __attribute__((ext_vector_type(8))) __bf16 bf16x8;
typedef __attribute__((ext_vector_type(8))) unsigned short ush8;
typedef __attribute__((ext_vector_type(4))) unsigned short ush4;

// async global->LDS DMA, 16B per lane; lds dest = uniform base + lane*16
#define GLOAD_LDS16(g, l) __builtin_amdgcn_global_load_lds( \
    (const __attribute__((address_space(1))) void*)(g),     \
    (__attribute__((address_space(3))) void*)(l), 16, 0, 0)

__device__ inline unsigned short bf16_rne(float f) {
    unsigned u = __builtin_bit_cast(unsigned, f);
    unsigned r = (u + 0x7FFFu + ((u >> 16) & 1u)) >> 16;
    return (unsigned short)r;
}
__device__ inline float bf16_f(unsigned short h) {
    unsigned u = ((unsigned)h) << 16;
    return __builtin_bit_cast(float, u);
}

#define MISC_B1_ (E_*H_/4)            // 512 float4
#define MISC_B2_ (E_*C_/4)            // 200 float4

// ---------------------------------------------------------------------------
// MEGA kernel: router GEMV + W1/W2 blend-transpose + b1/b2 blends, one launch.
// Router = round-9 LDS-direct body. REGISTER PREFETCH IS RETIRED: it spilled
// under BOTH the default cap (r8) and (256,2) (r10) — identical +97MB scratch
// WRITE signature, VGPR_Count pinned at 52 both times.
// W1 blend: 1 block per (e, chunk): two fully-SEQUENTIAL 32KB reads (float4),
// LDS [32][256] transpose, chunk-tiled store (gemm1's DMA format). This body
// is correctness-verified in r10.
// ---------------------------------------------------------------------------
__global__ __launch_bounds__(256) void mega_k(
        const float* __restrict__ x, const float* __restrict__ rw,
        const float* __restrict__ w1, const float* __restrict__ w2,
        const float* __restrict__ b1, const float* __restrict__ b2,
        unsigned short* __restrict__ Whi, unsigned short* __restrict__ Wlo,
        unsigned short* __restrict__ W2thi, unsigned short* __restrict__ W2tlo,
        float* __restrict__ B1b, float* __restrict__ B2b,
        double* __restrict__ lpart, const float* __restrict__ coeffs) {
    __shared__ char smem[36864];
    int bid = blockIdx.x;
    int t = threadIdx.x;

    if (bid < MEGA_R_) {
        // ---- router fp64 GEMV (LDS-direct staging, proven round-7/9 body) ----
        float  (*xs)[64][33] = (float(*)[64][33])smem;          // 33792 B
        double (*wls)[8]     = (double(*)[8])(smem + 33792);    // 2048 B
        int w = t >> 6, lane = t & 63;
        int rowblk = (bid & (RB_ - 1)) * 256;
        int s2     = bid >> 5;                 // K-slice
        int kbase  = s2 * RSEG_;
        int row0   = rowblk + w * 64;
        double c0 = (double)coeffs[0], c1 = (double)coeffs[1];

        double acc[8] = {0, 0, 0, 0, 0, 0, 0, 0};

        for (int kb = 0; kb < RSEG_; kb += 32) {
            #pragma unroll
            for (int it = 0; it < 8; it++) {
                int i = lane + it * 64;
                int r = i >> 3, c4 = i & 7;
                *(float4*)&xs[w][r][c4 * 4] =
                    *(const float4*)(x + (size_t)(row0 + r) * D_ + kbase + kb + c4 * 4);
            }
            if (w == 0) {
                #pragma unroll
                for (int it = 0; it < 4; it++) {
                    int i = lane + it * 64;
                    int k = i >> 3, ee = i & 7;
                    wls[k][ee] = c0 * (double)rw[(size_t)(kbase + kb + k) * 8 + ee]
                               + c1 * (double)rw[(size_t)(D_ + kbase + kb + k) * 8 + ee];
                }
            }
            __syncthreads();
            #pragma unroll
            for (int kk = 0; kk < 32; kk++) {
                double xv = (double)xs[w][lane][kk];
                double2 w01 = *(const double2*)&wls[kk][0];
                double2 w23 = *(const double2*)&wls[kk][2];
                double2 w45 = *(const double2*)&wls[kk][4];
                double2 w67 = *(const double2*)&wls[kk][6];
                acc[0] = fma(xv, w01.x, acc[0]);
                acc[1] = fma(xv, w01.y, acc[1]);
                acc[2] = fma(xv, w23.x, acc[2]);
                acc[3] = fma(xv, w23.y, acc[3]);
                acc[4] = fma(xv, w45.x, acc[4]);
                acc[5] = fma(xv, w45.y, acc[5]);
                acc[6] = fma(xv, w67.x, acc[6]);
                acc[7] = fma(xv, w67.y, acc[7]);
            }
            __syncthreads();
        }
        size_t base = ((size_t)s2 * B_ + row0 + lane) * 8;
        #pragma unroll
        for (int ee = 0; ee < 8; ee++) lpart[base + ee] = acc[ee];

    } else if (bid < MEGA_R_ + MEGA_W1_) {
        // ---- W1 blend: sequential 32KB reads, transpose, chunk-tiled store ----
        int lid = bid - MEGA_R_;
        int e  = lid / NCH_;
        int ci = lid - e * NCH_;
        int d0 = ci * 32;
        unsigned short* thi = (unsigned short*)smem;        // [32][256] = 16KB
        unsigned short* tlo = thi + 32 * 256;               // +16KB
        float c0 = coeffs[0], c1 = coeffs[1];
        const float* pa = w1 + ((size_t)(e * 2 + 0) * D_ + d0) * H_;
        const float* pb = w1 + ((size_t)(e * 2 + 1) * D_ + d0) * H_;
        #pragma unroll
        for (int it = 0; it < 8; it++) {
            int i4 = t + it * 256;                // 2048 float4 = 32d x 256h
            float4 va = *(const float4*)(pa + (size_t)i4 * 4);
            float4 vb = *(const float4*)(pb + (size_t)i4 * 4);
            float vv[4] = {c0 * va.x + c1 * vb.x, c0 * va.y + c1 * vb.y,
                           c0 * va.z + c1 * vb.z, c0 * va.w + c1 * vb.w};
            unsigned short h4[4], l4[4];
            #pragma unroll
            for (int j = 0; j < 4; j++) {
                unsigned short hi = bf16_rne(vv[j]);
                h4[j] = hi;
                l4[j] = bf16_rne(vv[j] - bf16_f(hi));
            }
            *(ush4*)&thi[i4 * 4] = *(const ush4*)h4;   // linear [d][h]
            *(ush4*)&tlo[i4 * 4] = *(const ush4*)l4;
        }
        __syncthreads();
        #pragma unroll
        for (int it = 0; it < 4; it++) {
            int j = t + it * 256;                 // 1024 ush8 = 256h x 4(d8)
            int h = j >> 2, d8 = (j & 3) * 8;
            unsigned short vh[8], vl[8];
            #pragma unroll
            for (int k2 = 0; k2 < 8; k2++) {
                vh[k2] = thi[(d8 + k2) * 256 + h];
                vl[k2] = tlo[(d8 + k2) * 256 + h];
            }
            size_t g = ((size_t)e * NCH_ + ci) * CHW_ + (size_t)h * 40 + d8;
            *(ush8*)(Whi + g) = *(const ush8*)vh;
            *(ush8*)(Wlo + g) = *(const ush8*)vl;
        }

    } else if (bid < MEGA_R_ + MEGA_W1_ + MEGA_W2_) {
        // ---- W2 blend + hi/lo split + transpose to [e][c][k] ----
        int lid = bid - (MEGA_R_ + MEGA_W1_);
        int c = lid % C_, e = lid / C_;
        int k = t;
        float c0 = coeffs[0], c1 = coeffs[1];
        float v = c0 * w2[((size_t)(e * 2 + 0) * H_ + k) * C_ + c]
                + c1 * w2[((size_t)(e * 2 + 1) * H_ + k) * C_ + c];
        unsigned short hi = bf16_rne(v);
        W2thi[(size_t)(e * C_ + c) * H_ + k] = hi;
        W2tlo[(size_t)(e * C_ + c) * H_ + k] = bf16_rne(v - bf16_f(hi));

    } else {
        // ---- b1 / b2 blends ----
        int gid = (bid - (MEGA_R_ + MEGA_W1_ + MEGA_W2_)) * 256 + t;
        float c0 = coeffs[0], c1 = coeffs[1];
        if (gid < MISC_B1_) {
            const float4* p = (const float4*)b1;
            int e = gid / (H_ / 4), r = gid - e * (H_ / 4);
            float4 a = p[(e * 2 + 0) * (H_ / 4) + r];
            float4 bq = p[(e * 2 + 1) * (H_ / 4) + r];
            float4 o;
            o.x = c0 * a.x + c1 * bq.x;
            o.y = c0 * a.y + c1 * bq.y;
            o.z = c0 * a.z + c1 * bq.z;
            o.w = c0 * a.w + c1 * bq.w;
            ((float4*)B1b)[gid] = o;
        } else if (gid < MISC_B1_ + MISC_B2_) {
            int g2 = gid - MISC_B1_;
            const float4* p = (const float4*)b2;
            int e = g2 / (C_ / 4), r = g2 - e * (C_ / 4);
            float4 a = p[(e * 2 + 0) * (C_ / 4) + r];
            float4 bq = p[(e * 2 + 1) * (C_ / 4) + r];
            float4 o;
            o.x = c0 * a.x + c1 * bq.x;
            o.y = c0 * a.y + c1 * bq.y;
            o.z = c0 * a.z + c1 * bq.z;
            o.w = c0 * a.w + c1 * bq.w;
            ((float4*)B2b)[g2] = o;
        }
    }
}

// ---------------------------------------------------------------------------
// argmax + per-block histogram. fp64, strict > (np first-max), coalesced
// double2 row reads. No global atomics.
// ---------------------------------------------------------------------------
__global__ __launch_bounds__(256) void argmax_hist_k(
        const double* __restrict__ lpart, const float* __restrict__ rb,
        const float* __restrict__ coeffs, int* __restrict__ idx,
        int* __restrict__ hist) {
    __shared__ int scnt[8];
    int t = threadIdx.x;
    if (t < 8) scnt[t] = 0;
    __syncthreads();
    int b = blockIdx.x * 256 + t;
    double c0 = (double)coeffs[0], c1 = (double)coeffs[1];
    double l[8];
    #pragma unroll
    for (int e = 0; e < 8; e++)
        l[e] = c0 * (double)rb[e] + c1 * (double)rb[8 + e];
    for (int s2 = 0; s2 < RKS_; s2++) {
        const double2* pp = (const double2*)(lpart + ((size_t)s2 * B_ + b) * 8);
        double2 v0 = pp[0], v1 = pp[1], v2 = pp[2], v3 = pp[3];
        l[0] += v0.x; l[1] += v0.y; l[2] += v1.x; l[3] += v1.y;
        l[4] += v2.x; l[5] += v2.y; l[6] += v3.x; l[7] += v3.y;
    }
    double best = -1e300;
    int bi = 0;
    #pragma unroll
    for (int e = 0; e < 8; e++)
        if (l[e] > best) { best = l[e]; bi = e; }
    idx[b] = bi;
    atomicAdd(&scnt[bi], 1);       // LDS atomic only
    __syncthreads();
    if (t < 8) hist[blockIdx.x * 8 + t] = scnt[t];
}

// ---------------------------------------------------------------------------
// scatter from histograms: zero global atomics, deterministic order
// (row-ascending within expert). Block 0 also writes cnt/off/tmap/tmap2/ntl.
// ---------------------------------------------------------------------------
__global__ __launch_bounds__(256) void scatter2_k(
        const int* __restrict__ idx, const int* __restrict__ hist,
        int* __restrict__ order, int* __restrict__ cnt, int* __restrict__ off,
        int* __restrict__ tmap, int* __restrict__ tmap2, int* __restrict__ ntl) {
    __shared__ int sbi[256];
    __shared__ int stot[8];
    __shared__ int sbase[8];
    int b0 = blockIdx.x, t = threadIdx.x;
    int b = b0 * 256 + t;
    int mybi = idx[b];
    sbi[t] = mybi;
    if (t < 8) {
        int tot = 0, pre = 0;
        for (int bb = 0; bb < RB_; bb++) {
            int h = hist[bb * 8 + t];
            if (bb < b0) pre += h;
            tot += h;
        }
        stot[t] = tot;
        sbase[t] = pre;
    }
    __syncthreads();
    if (t < 8) {
        int o = 0;
        for (int j = 0; j < t; j++) o += stot[j];
        sbase[t] += o;
    }
    __syncthreads();
    int rank = 0;
    for (int i = 0; i < 256; i++) {
        int v = sbi[i];
        rank += (i < t && v == mybi) ? 1 : 0;
    }
    order[sbase[mybi] + rank] = (mybi << 16) | b;

    if (b0 == 0 && t == 0) {
        int s = 0;
        for (int e = 0; e < E_; e++) { cnt[e] = stot[e]; off[e] = s; s += stot[e]; }
        int nt = 0;
        for (int e = 0; e < E_; e++)
            for (int t0 = 0; t0 < stot[e]; t0 += 64)
                tmap[nt++] = (e << 16) | t0;
        ntl[0] = nt;
        int nt2 = 0;
        for (int e = 0; e < E_; e++)
            for (int t0 = 0; t0 < stot[e]; t0 += 16)
                tmap2[nt2++] = (e << 16) | t0;
        ntl[1] = nt2;
    }
}

// ---------------------------------------------------------------------------
// GEMM1 via bf16x2-split MFMA (hh, lh, hl, ll), fp32 AGPR acc.
// Grid (KS, NTMAX): blockIdx.x = K-slice s fastest -> slice s pins to XCD s.
// Weight staging via global_load_lds DMA from the chunk-tiled Whi/Wlo format.
// MODE=1: plain stores to per-slice partials, then SPLIT-K COMPLETION:
//   store partial -> __threadfence (release) -> atomicAdd(tcnt[tile]);
//   the 8th finisher acquires, reduces slices 0..7 IN ORDER (identical to
//   the verified reduce_gelu_k), adds b1, exact GELU, writes slice 0.
//   Moves the 64MB reduce read under other tiles' MFMA shadow.
// MODE=0: atomicAdd fallback (no completion logic).
// ---------------------------------------------------------------------------
template<int MODE>
__global__ __launch_bounds__(256, 3) void gemm1_t(
        const float* __restrict__ x, const unsigned short* __restrict__ Whi,
        const unsigned short* __restrict__ Wlo, const int* __restrict__ order,
        const int* __restrict__ cnt, const int* __restrict__ off,
        const int* __restrict__ tmap, const int* __restrict__ ntl,
        const float* __restrict__ B1b, int* __restrict__ tcnt,
        float* __restrict__ dst) {
    int tid = blockIdx.y;
    if (tid >= ntl[0]) return;
    int tm = tmap[tid];
    int e = tm >> 16, tile0 = tm & 0xFFFF;
    int ce = cnt[e];
    int s = blockIdx.x;

    __shared__ int rows[64];
    __shared__ int sdone;
    __shared__ unsigned short xs_hi[64 * 40];
    __shared__ unsigned short xs_lo[64 * 40];
    __shared__ unsigned short ws_hi[256 * 40];
    __shared__ unsigned short ws_lo[256 * 40];

    int t = threadIdx.x;
    if (t < 64) {
        int i = tile0 + t;
        rows[t] = (i < ce) ? (order[off[e] + i] & 0xFFFF) : -1;
    }
    __syncthreads();
    int xrow0 = rows[0];

    int lane = t & 63, w = t >> 6;
    int lr = lane & 15, quad = lane >> 4;
    int kbase = s * KSEG_;
    int wuni = t & ~63;       // wave-uniform lane-0 thread index

    f32x4 acc[4][4];
    #pragma unroll
    for (int mt = 0; mt < 4; mt++)
        #pragma unroll
        for (int nt = 0; nt < 4; nt++)
            acc[mt][nt] = (f32x4){0.f, 0.f, 0.f, 0.f};

    for (int kb = 0; kb < KSEG_; kb += 32) {
        // ---- weight staging: async DMA of the 20480B chunk blocks ----
        {
            int ci = (kbase + kb) >> 5;
            const unsigned short* ph = Whi + ((size_t)e * NCH_ + ci) * CHW_;
            const unsigned short* pl = Wlo + ((size_t)e * NCH_ + ci) * CHW_;
            #pragma unroll
            for (int j = 0; j < 5; j++) {
                GLOAD_LDS16(ph + ((size_t)(j * 256 + t)) * 8,
                            ws_hi + (size_t)(j * 256 + wuni) * 8);
                GLOAD_LDS16(pl + ((size_t)(j * 256 + t)) * 8,
                            ws_lo + (size_t)(j * 256 + wuni) * 8);
            }
        }
        // ---- x staging: load + hi/lo split (VALU, overlaps the DMA) ----
        #pragma unroll
        for (int it = 0; it < 2; it++) {
            int i = t + it * 256;
            int rr = i >> 3, sg = i & 7;
            int row = rows[rr];
            if (row < 0) row = xrow0;
            float4 v = *(const float4*)(x + (size_t)row * D_ + kbase + kb + sg * 4);
            unsigned short h4[4], l4[4];
            float vv[4] = {v.x, v.y, v.z, v.w};
            #pragma unroll
            for (int j = 0; j < 4; j++) {
                unsigned short hi = bf16_rne(vv[j]);
                h4[j] = hi;
                l4[j] = bf16_rne(vv[j] - bf16_f(hi));
            }
            *(ush4*)&xs_hi[rr * 40 + sg * 4] = *(const ush4*)h4;
            *(ush4*)&xs_lo[rr * 40 + sg * 4] = *(const ush4*)l4;
        }
        __syncthreads();

        bf16x8 ah[4], al[4], bh[4], bl[4];
        #pragma unroll
        for (int mt = 0; mt < 4; mt++) {
            ah[mt] = __builtin_bit_cast(bf16x8, *(const ush8*)&xs_hi[(mt * 16 + lr) * 40 + quad * 8]);
            al[mt] = __builtin_bit_cast(bf16x8, *(const ush8*)&xs_lo[(mt * 16 + lr) * 40 + quad * 8]);
        }
        #pragma unroll
        for (int nt = 0; nt < 4; nt++) {
            int col = w * 64 + nt * 16 + lr;
            bh[nt] = __builtin_bit_cast(bf16x8, *(const ush8*)&ws_hi[col * 40 + quad * 8]);
            bl[nt] = __builtin_bit_cast(bf16x8, *(const ush8*)&ws_lo[col * 40 + quad * 8]);
        }
        #pragma unroll
        for (int mt = 0; mt < 4; mt++)
            #pragma unroll
            for (int nt = 0; nt < 4; nt++) {
                acc[mt][nt] = __builtin_amdgcn_mfma_f32_16x16x32_bf16(ah[mt], bh[nt], acc[mt][nt], 0, 0, 0);
                acc[mt][nt] = __builtin_amdgcn_mfma_f32_16x16x32_bf16(al[mt], bh[nt], acc[mt][nt], 0, 0, 0);
                acc[mt][nt] = __builtin_amdgcn_mfma_f32_16x16x32_bf16(ah[mt], bl[nt], acc[mt][nt], 0, 0, 0);
                acc[mt][nt] = __builtin_amdgcn_mfma_f32_16x16x32_bf16(al[mt], bl[nt], acc[mt][nt], 0, 0, 0);
            }
        __syncthreads();
    }

    size_t p0 = (size_t)off[e] + tile0;
    if (MODE == 1) {
        float* dp = dst + ((size_t)s * B_ + p0) * H_;
        #pragma unroll
        for (int mt = 0; mt < 4; mt++) {
            int rl = mt * 16 + quad * 4;
            #pragma unroll
            for (int nt = 0; nt < 4; nt++) {
                int col = w * 64 + nt * 16 + lr;
                #pragma unroll
                for (int rg = 0; rg < 4; rg++) {
                    if (tile0 + rl + rg < ce)
                        dp[(size_t)(rl + rg) * H_ + col] = acc[mt][nt][rg];
                }
            }
        }
        // ---- split-K completion: last block reduces + bias + GELU ----
        __threadfence();                         // release this block's partial
        if (t == 0) sdone = atomicAdd(&tcnt[tid], 1);
        __syncthreads();
        if (sdone == KS_ - 1) {
            __threadfence();                     // acquire other blocks' partials
            #pragma unroll
            for (int it = 0; it < 16; it++) {
                int i = t + it * 256;            // 4096 float4 = 64 rows x 64
                int r = i >> 6, c4 = (i & 63) * 4;
                if (tile0 + r < ce) {
                    size_t o = (p0 + r) * H_ + c4;
                    float4 a = *(const float4*)(dst + o);
                    #pragma unroll
                    for (int s2 = 1; s2 < KS_; s2++) {
                        const float* sp = dst + (size_t)s2 * B_ * H_ + o;
                        float4 b = *(const float4*)sp;
                        a.x += b.x; a.y += b.y; a.z += b.z; a.w += b.w;
                    }
                    const float4 bb = *(const float4*)(B1b + e * H_ + c4);
                    float pre[4] = {a.x + bb.x, a.y + bb.y, a.z + bb.z, a.w + bb.w};
                    float4 og;
                    og.x = 0.5f * pre[0] * (1.0f + erff(pre[0] * 0.70710678118654752440f));
                    og.y = 0.5f * pre[1] * (1.0f + erff(pre[1] * 0.70710678118654752440f));
                    og.z = 0.5f * pre[2] * (1.0f + erff(pre[2] * 0.70710678118654752440f));
                    og.w = 0.5f * pre[3] * (1.0f + erff(pre[3] * 0.70710678118654752440f));
                    *(float4*)(dst + o) = og;
                }
            }
        }
    } else {
        #pragma unroll
        for (int mt = 0; mt < 4; mt++) {
            int rl = mt * 16 + quad * 4;
            #pragma unroll
            for (int nt = 0; nt < 4; nt++) {
                int col = w * 64 + nt * 16 + lr;
                #pragma unroll
                for (int rg = 0; rg < 4; rg++) {
                    if (tile0 + rl + rg < ce)
                        atomicAdd(&dst[(p0 + rl + rg) * H_ + col], acc[mt][nt][rg]);
                }
            }
        }
    }
}

// ---------------------------------------------------------------------------
// bias + exact GELU, in place on hws (fp32) — legacy fallback path
// ---------------------------------------------------------------------------
__global__ __launch_bounds__(256) void bias_gelu_k(
        float* __restrict__ hws, const float* __restrict__ B1b,
        const int* __restrict__ order) {
    int gid = blockIdx.x * 256 + threadIdx.x;
    int p = gid >> 6, c4 = (gid & 63) * 4;
    int e = order[p] >> 16;
    float4 v = *(const float4*)(hws + (size_t)p * H_ + c4);
    const float4 bb = *(const float4*)(B1b + e * H_ + c4);
    float pre[4] = {v.x + bb.x, v.y + bb.y, v.z + bb.z, v.w + bb.w};
    float4 o;
    o.x = 0.5f * pre[0] * (1.0f + erff(pre[0] * 0.70710678118654752440f));
    o.y = 0.5f * pre[1] * (1.0f + erff(pre[1] * 0.70710678118654752440f));
    o.z = 0.5f * pre[2] * (1.0f + erff(pre[2] * 0.70710678118654752440f));
    o.w = 0.5f * pre[3] * (1.0f + erff(pre[3] * 0.70710678118654752440f));
    *(float4*)(hws + (size_t)p * H_ + c4) = o;
}

// ---------------------------------------------------------------------------
// GEMM2, 16-row tiles, 4 waves K-split over H, LDS cross-wave reduce.
// A = hws (post-GELU finals, written by gemm1's split-K completion).
// ---------------------------------------------------------------------------
__global__ __launch_bounds__(256) void gemm2_k(
        const float* __restrict__ hws,
        const unsigned short* __restrict__ W2thi, const unsigned short* __restrict__ W2tlo,
        const float* __restrict__ B2b, const int* __restrict__ order,
        const int* __restrict__ cnt, const int* __restrict__ off,
        const int* __restrict__ tmap2, const int* __restrict__ ntl,
        float* __restrict__ out) {
    int tid = blockIdx.x;
    if (tid >= ntl[1]) return;
    int tm = tmap2[tid];
    int e = tm >> 16, tile0 = tm & 0xFFFF;
    int ce = cnt[e];

    __shared__ int rows[16];
    __shared__ float red[3][64][28];

    int t = threadIdx.x;
    if (t < 16) {
        int i = tile0 + t;
        rows[t] = (i < ce) ? (order[off[e] + i] & 0xFFFF) : -1;
    }
    __syncthreads();

    int lane = t & 63, w = t >> 6;
    int m = lane & 15, q = lane >> 4;
    int p = off[e] + tile0 + ((tile0 + m < ce) ? m : 0);

    f32x4 acc[7];
    #pragma unroll
    for (int nt = 0; nt < 7; nt++) acc[nt] = (f32x4){0.f, 0.f, 0.f, 0.f};

    const unsigned short* w2h = W2thi + (size_t)e * C_ * H_;
    const unsigned short* w2l = W2tlo + (size_t)e * C_ * H_;

    #pragma unroll
    for (int si = 0; si < 2; si++) {
        int s = w * 2 + si;
        int k0 = s * 32 + q * 8;
        size_t o = (size_t)p * H_ + k0;
        float4 v0 = *(const float4*)(hws + o);
        float4 v1 = *(const float4*)(hws + o + 4);
        float f[8] = {v0.x, v0.y, v0.z, v0.w, v1.x, v1.y, v1.z, v1.w};
        unsigned short hh[8], lo[8];
        #pragma unroll
        for (int j = 0; j < 8; j++) {
            unsigned short hi = bf16_rne(f[j]);
            hh[j] = hi;
            lo[j] = bf16_rne(f[j] - bf16_f(hi));
        }
        bf16x8 ah = __builtin_bit_cast(bf16x8, *(const ush8*)hh);
        bf16x8 al = __builtin_bit_cast(bf16x8, *(const ush8*)lo);
        #pragma unroll
        for (int nt = 0; nt < 7; nt++) {
            // cols >= C_ read past the unpadded plane into adjacent ws arrays;
            // results land in discarded lanes only.
            size_t bo = (size_t)(nt * 16 + m) * H_ + k0;
            bf16x8 bh = __builtin_bit_cast(bf16x8, *(const ush8*)(w2h + bo));
            bf16x8 bl = __builtin_bit_cast(bf16x8, *(const ush8*)(w2l + bo));
            acc[nt] = __builtin_amdgcn_mfma_f32_16x16x32_bf16(ah, bh, acc[nt], 0, 0, 0);
            acc[nt] = __builtin_amdgcn_mfma_f32_16x16x32_bf16(al, bh, acc[nt], 0, 0, 0);
            acc[nt] = __builtin_amdgcn_mfma_f32_16x16x32_bf16(ah, bl, acc[nt], 0, 0, 0);
            acc[nt] = __builtin_amdgcn_mfma_f32_16x16x32_bf16(al, bl, acc[nt], 0, 0, 0);
        }
    }

    if (w > 0) {
        #pragma unroll
        for (int nt = 0; nt < 7; nt++)
            #pragma unroll
            for (int i = 0; i < 4; i++)
                red[w - 1][lane][nt * 4 + i] = acc[nt][i];
    }
    __syncthreads();
    if (w == 0) {
        #pragma unroll
        for (int nt = 0; nt < 7; nt++)
            #pragma unroll
            for (int i = 0; i < 4; i++)
                acc[nt][i] = ((acc[nt][i] + red[0][lane][nt * 4 + i])
                              + red[1][lane][nt * 4 + i]) + red[2][lane][nt * 4 + i];
        #pragma unroll
        for (int nt = 0; nt < 7; nt++) {
            int c = nt * 16 + m;
            if (c >= C_) continue;
            float bias = B2b[e * C_ + c];
            #pragma unroll
            for (int i = 0; i < 4; i++) {
                int grow = q * 4 + i;
                if (tile0 + grow < ce)
                    out[(size_t)rows[grow] * C_ + c] = acc[nt][i] + bias;
            }
        }
    }
}

// ---------------------------------------------------------------------------
extern "C" void kernel_launch(void* const* d_in, const int* in_sizes, int n_in,
                              void* d_out, int out_size, void* d_ws, size_t ws_size,
                              hipStream_t stream) {
    const float* x        = (const float*)d_in[0];
    const float* coeffs   = (const float*)d_in[1];
    const float* router_w = (const float*)d_in[2];
    const float* router_b = (const float*)d_in[3];
    const float* w1       = (const float*)d_in[4];
    const float* b1       = (const float*)d_in[5];
    const float* w2       = (const float*)d_in[6];
    const float* b2       = (const float*)d_in[7];
    float* out = (float*)d_out;

    // workspace layout: weight planes chunk-tiled (E*NCH*CHW ushorts each)
    unsigned short* Whi   = (unsigned short*)d_ws;        // E*96*10240 ush (15.7MB)
    unsigned short* Wlo   = Whi + (size_t)E_ * NCH_ * CHW_;
    unsigned short* W2thi = Wlo + (size_t)E_ * NCH_ * CHW_;  // E*C*H ush
    unsigned short* W2tlo = W2thi + (size_t)E_ * C_ * H_;
    float* B1b  = (float*)(W2tlo + (size_t)E_ * C_ * H_); // E*H
    float* B2b  = B1b + (size_t)E_ * H_;                  // E*C
    int* order  = (int*)(B2b + E_ * C_);                  // B (packed e<<16|b)
    int* cnt    = order + B_;                             // 8
    int* off    = cnt + E_;                               // 8
    int* tmap   = off + E_;                               // NTMAX
    int* tmap2  = tmap + NTMAX_;                          // NT2MAX
    int* ntl    = tmap2 + NT2MAX_;                        // 4
    int* idx    = ntl + 4;                                // B ints
    int* hist   = idx + B_;                               // RB*8 = 256 ints
    int* tcnt   = hist + 256;                             // NTMAX (pad to 144)
    float* hws  = (float*)(tcnt + 144);                   // B*H f32 (slice 0)
    // lpart (RKS*B*8 f64 = 8 MB) aliases hws slice 0 exactly; dead before
    // gemm1 (use_part) / before the hws memset (fallback).
    double* lpart = (double*)hws;

    size_t prefix_bytes = (size_t)((char*)hws - (char*)d_ws);
    int use_part = (ws_size >= prefix_bytes + (size_t)KS_ * B_ * H_ * sizeof(float) + 256) ? 1 : 0;

    // one fused launch: router + W1/W2 blends + b1/b2 blends (overlapped)
    mega_k<<<dim3(MEGA_TOT_), 256, 0, stream>>>(
        x, router_w, w1, w2, b1, b2, Whi, Wlo, W2thi, W2tlo, B1b, B2b,
        lpart, coeffs);

    argmax_hist_k<<<dim3(RB_), 256, 0, stream>>>(lpart, router_b, coeffs, idx, hist);
    scatter2_k<<<dim3(RB_), 256, 0, stream>>>(idx, hist, order, cnt, off,
                                              tmap, tmap2, ntl);

    if (use_part) {
        // zero the split-K completion counters (tiny)
        hipMemsetAsync(tcnt, 0, NTMAX_ * sizeof(int), stream);
        // gemm1 writes partials AND reduces+GELUs into slice 0 (split-K
        // completion); no hws memset needed.
        gemm1_t<1><<<dim3(KS_, NTMAX_), 256, 0, stream>>>(x, Whi, Wlo, order, cnt,
                                                          off, tmap, ntl, B1b,
                                                          tcnt, hws);
        gemm2_k<<<dim3(NT2MAX_), 256, 0, stream>>>(hws, W2thi, W2tlo, B2b,
                                                   order, cnt, off, tmap2, ntl, out);
    } else {
        // zero hws (lpart alias dead), atomic partial sums
        hipMemsetAsync(hws, 0, (size_t)B_ * H_ * sizeof(float), stream);
        gemm1_t<0><<<dim3(KS_, NTMAX_), 256, 0, stream>>>(x, Whi, Wlo, order, cnt,
                                                          off, tmap, ntl, B1b,
                                                          tcnt, hws);
        bias_gelu_k<<<dim3(B_ * H_ / 4 / 256), 256, 0, stream>>>(hws, B1b, order);
        gemm2_k<<<dim3(NT2MAX_), 256, 0, stream>>>(hws, W2thi, W2tlo, B2b,
                                                   order, cnt, off, tmap2, ntl, out);
    }
}

// Round 12
// 332.604 us; speedup vs baseline: 1.9659x; 1.9659x over previous
//
#include <hip/hip_runtime.h>
#include <math.h>

#define B_  8192
#define E_  8
#define D_  3072
#define H_  256
#define C_  100
#define DH_ (D_*H_)
#define HC_ (H_*C_)
#define KS_ 8            // K splits in gemm1
#define KSEG_ (D_/KS_)   // 384
#define RKS_ 16          // K splits in router
#define RSEG_ (D_/RKS_)  // 192
#define RB_ (B_/256)     // 32 row-blocks of 256 rows
#define NTMAX_ 136       // max 64-row tiles over all experts (128+8 slack)
#define NT2MAX_ 528      // max 16-row tiles (512+16 slack)
#define NCH_ (D_/32)     // 96 32-k chunks
#define CHW_ 10240       // ushorts per weight chunk block: 256 cols * 40

// mega-kernel block ranges (router first: it's on the critical path)
#define MEGA_R_   (RB_*RKS_)          // 512 router blocks (4 waves x 64 rows)
#define MEGA_W1_  (E_*NCH_)           // 768 W1 chunk tiles (1 block per (e,ci))
#define MEGA_W2_  (C_*E_)             // 800 blendw2t columns
#define MEGA_BB_  3                   // b1/b2 blend blocks
#define MEGA_TOT_ (MEGA_R_ + MEGA_W1_ + MEGA_W2_ + MEGA_BB_)

typedef __attribute__((ext_vector_type(4))) float  f32x4;
typedef __attribute__((ext_vector_type(8))) __bf16 bf16x8;
typedef __attribute__((ext_vector_type(8))) unsigned short ush8;
typedef __attribute__((ext_vector_type(4))) unsigned short ush4;

// async global->LDS DMA, 16B per lane; lds dest = uniform base + lane*16
#define GLOAD_LDS16(g, l) __builtin_amdgcn_global_load_lds( \
    (const __attribute__((address_space(1))) void*)(g),     \
    (__attribute__((address_space(3))) void*)(l), 16, 0, 0)

__device__ inline unsigned short bf16_rne(float f) {
    unsigned u = __builtin_bit_cast(unsigned, f);
    unsigned r = (u + 0x7FFFu + ((u >> 16) & 1u)) >> 16;
    return (unsigned short)r;
}
__device__ inline float bf16_f(unsigned short h) {
    unsigned u = ((unsigned)h) << 16;
    return __builtin_bit_cast(float, u);
}

#define MISC_B1_ (E_*H_/4)            // 512 float4
#define MISC_B2_ (E_*C_/4)            // 200 float4

// ---------------------------------------------------------------------------
// MEGA kernel: router GEMV + W1/W2 blend-transpose + b1/b2 blends, one launch.
// Router = LDS-direct body (register prefetch RETIRED: spilled under default
// cap (r8) AND (256,2) (r10), +97MB scratch WRITE signature both times).
// Split-K completion also RETIRED (r11: __threadfence serialization, 6x).
// W1 blend: 1 block per (e, chunk): two fully-SEQUENTIAL 32KB reads (float4),
// LDS [32][256] transpose, chunk-tiled store (gemm1's DMA format).
// ---------------------------------------------------------------------------
__global__ __launch_bounds__(256) void mega_k(
        const float* __restrict__ x, const float* __restrict__ rw,
        const float* __restrict__ w1, const float* __restrict__ w2,
        const float* __restrict__ b1, const float* __restrict__ b2,
        unsigned short* __restrict__ Whi, unsigned short* __restrict__ Wlo,
        unsigned short* __restrict__ W2thi, unsigned short* __restrict__ W2tlo,
        float* __restrict__ B1b, float* __restrict__ B2b,
        double* __restrict__ lpart, const float* __restrict__ coeffs) {
    __shared__ char smem[36864];
    int bid = blockIdx.x;
    int t = threadIdx.x;

    if (bid < MEGA_R_) {
        // ---- router fp64 GEMV (LDS-direct staging, proven round-7/9 body) ----
        float  (*xs)[64][33] = (float(*)[64][33])smem;          // 33792 B
        double (*wls)[8]     = (double(*)[8])(smem + 33792);    // 2048 B
        int w = t >> 6, lane = t & 63;
        int rowblk = (bid & (RB_ - 1)) * 256;
        int s2     = bid >> 5;                 // K-slice
        int kbase  = s2 * RSEG_;
        int row0   = rowblk + w * 64;
        double c0 = (double)coeffs[0], c1 = (double)coeffs[1];

        double acc[8] = {0, 0, 0, 0, 0, 0, 0, 0};

        for (int kb = 0; kb < RSEG_; kb += 32) {
            #pragma unroll
            for (int it = 0; it < 8; it++) {
                int i = lane + it * 64;
                int r = i >> 3, c4 = i & 7;
                *(float4*)&xs[w][r][c4 * 4] =
                    *(const float4*)(x + (size_t)(row0 + r) * D_ + kbase + kb + c4 * 4);
            }
            if (w == 0) {
                #pragma unroll
                for (int it = 0; it < 4; it++) {
                    int i = lane + it * 64;
                    int k = i >> 3, ee = i & 7;
                    wls[k][ee] = c0 * (double)rw[(size_t)(kbase + kb + k) * 8 + ee]
                               + c1 * (double)rw[(size_t)(D_ + kbase + kb + k) * 8 + ee];
                }
            }
            __syncthreads();
            #pragma unroll
            for (int kk = 0; kk < 32; kk++) {
                double xv = (double)xs[w][lane][kk];
                double2 w01 = *(const double2*)&wls[kk][0];
                double2 w23 = *(const double2*)&wls[kk][2];
                double2 w45 = *(const double2*)&wls[kk][4];
                double2 w67 = *(const double2*)&wls[kk][6];
                acc[0] = fma(xv, w01.x, acc[0]);
                acc[1] = fma(xv, w01.y, acc[1]);
                acc[2] = fma(xv, w23.x, acc[2]);
                acc[3] = fma(xv, w23.y, acc[3]);
                acc[4] = fma(xv, w45.x, acc[4]);
                acc[5] = fma(xv, w45.y, acc[5]);
                acc[6] = fma(xv, w67.x, acc[6]);
                acc[7] = fma(xv, w67.y, acc[7]);
            }
            __syncthreads();
        }
        size_t base = ((size_t)s2 * B_ + row0 + lane) * 8;
        #pragma unroll
        for (int ee = 0; ee < 8; ee++) lpart[base + ee] = acc[ee];

    } else if (bid < MEGA_R_ + MEGA_W1_) {
        // ---- W1 blend: sequential 32KB reads, transpose, chunk-tiled store ----
        int lid = bid - MEGA_R_;
        int e  = lid / NCH_;
        int ci = lid - e * NCH_;
        int d0 = ci * 32;
        unsigned short* thi = (unsigned short*)smem;        // [32][256] = 16KB
        unsigned short* tlo = thi + 32 * 256;               // +16KB
        float c0 = coeffs[0], c1 = coeffs[1];
        const float* pa = w1 + ((size_t)(e * 2 + 0) * D_ + d0) * H_;
        const float* pb = w1 + ((size_t)(e * 2 + 1) * D_ + d0) * H_;
        #pragma unroll
        for (int it = 0; it < 8; it++) {
            int i4 = t + it * 256;                // 2048 float4 = 32d x 256h
            float4 va = *(const float4*)(pa + (size_t)i4 * 4);
            float4 vb = *(const float4*)(pb + (size_t)i4 * 4);
            float vv[4] = {c0 * va.x + c1 * vb.x, c0 * va.y + c1 * vb.y,
                           c0 * va.z + c1 * vb.z, c0 * va.w + c1 * vb.w};
            unsigned short h4[4], l4[4];
            #pragma unroll
            for (int j = 0; j < 4; j++) {
                unsigned short hi = bf16_rne(vv[j]);
                h4[j] = hi;
                l4[j] = bf16_rne(vv[j] - bf16_f(hi));
            }
            *(ush4*)&thi[i4 * 4] = *(const ush4*)h4;   // linear [d][h]
            *(ush4*)&tlo[i4 * 4] = *(const ush4*)l4;
        }
        __syncthreads();
        #pragma unroll
        for (int it = 0; it < 4; it++) {
            int j = t + it * 256;                 // 1024 ush8 = 256h x 4(d8)
            int h = j >> 2, d8 = (j & 3) * 8;
            unsigned short vh[8], vl[8];
            #pragma unroll
            for (int k2 = 0; k2 < 8; k2++) {
                vh[k2] = thi[(d8 + k2) * 256 + h];
                vl[k2] = tlo[(d8 + k2) * 256 + h];
            }
            size_t g = ((size_t)e * NCH_ + ci) * CHW_ + (size_t)h * 40 + d8;
            *(ush8*)(Whi + g) = *(const ush8*)vh;
            *(ush8*)(Wlo + g) = *(const ush8*)vl;
        }

    } else if (bid < MEGA_R_ + MEGA_W1_ + MEGA_W2_) {
        // ---- W2 blend + hi/lo split + transpose to [e][c][k] ----
        int lid = bid - (MEGA_R_ + MEGA_W1_);
        int c = lid % C_, e = lid / C_;
        int k = t;
        float c0 = coeffs[0], c1 = coeffs[1];
        float v = c0 * w2[((size_t)(e * 2 + 0) * H_ + k) * C_ + c]
                + c1 * w2[((size_t)(e * 2 + 1) * H_ + k) * C_ + c];
        unsigned short hi = bf16_rne(v);
        W2thi[(size_t)(e * C_ + c) * H_ + k] = hi;
        W2tlo[(size_t)(e * C_ + c) * H_ + k] = bf16_rne(v - bf16_f(hi));

    } else {
        // ---- b1 / b2 blends ----
        int gid = (bid - (MEGA_R_ + MEGA_W1_ + MEGA_W2_)) * 256 + t;
        float c0 = coeffs[0], c1 = coeffs[1];
        if (gid < MISC_B1_) {
            const float4* p = (const float4*)b1;
            int e = gid / (H_ / 4), r = gid - e * (H_ / 4);
            float4 a = p[(e * 2 + 0) * (H_ / 4) + r];
            float4 bq = p[(e * 2 + 1) * (H_ / 4) + r];
            float4 o;
            o.x = c0 * a.x + c1 * bq.x;
            o.y = c0 * a.y + c1 * bq.y;
            o.z = c0 * a.z + c1 * bq.z;
            o.w = c0 * a.w + c1 * bq.w;
            ((float4*)B1b)[gid] = o;
        } else if (gid < MISC_B1_ + MISC_B2_) {
            int g2 = gid - MISC_B1_;
            const float4* p = (const float4*)b2;
            int e = g2 / (C_ / 4), r = g2 - e * (C_ / 4);
            float4 a = p[(e * 2 + 0) * (C_ / 4) + r];
            float4 bq = p[(e * 2 + 1) * (C_ / 4) + r];
            float4 o;
            o.x = c0 * a.x + c1 * bq.x;
            o.y = c0 * a.y + c1 * bq.y;
            o.z = c0 * a.z + c1 * bq.z;
            o.w = c0 * a.w + c1 * bq.w;
            ((float4*)B2b)[g2] = o;
        }
    }
}

// ---------------------------------------------------------------------------
// argmax + per-block histogram. fp64, strict > (np first-max), coalesced
// double2 row reads. No global atomics.
// ---------------------------------------------------------------------------
__global__ __launch_bounds__(256) void argmax_hist_k(
        const double* __restrict__ lpart, const float* __restrict__ rb,
        const float* __restrict__ coeffs, int* __restrict__ idx,
        int* __restrict__ hist) {
    __shared__ int scnt[8];
    int t = threadIdx.x;
    if (t < 8) scnt[t] = 0;
    __syncthreads();
    int b = blockIdx.x * 256 + t;
    double c0 = (double)coeffs[0], c1 = (double)coeffs[1];
    double l[8];
    #pragma unroll
    for (int e = 0; e < 8; e++)
        l[e] = c0 * (double)rb[e] + c1 * (double)rb[8 + e];
    for (int s2 = 0; s2 < RKS_; s2++) {
        const double2* pp = (const double2*)(lpart + ((size_t)s2 * B_ + b) * 8);
        double2 v0 = pp[0], v1 = pp[1], v2 = pp[2], v3 = pp[3];
        l[0] += v0.x; l[1] += v0.y; l[2] += v1.x; l[3] += v1.y;
        l[4] += v2.x; l[5] += v2.y; l[6] += v3.x; l[7] += v3.y;
    }
    double best = -1e300;
    int bi = 0;
    #pragma unroll
    for (int e = 0; e < 8; e++)
        if (l[e] > best) { best = l[e]; bi = e; }
    idx[b] = bi;
    atomicAdd(&scnt[bi], 1);       // LDS atomic only
    __syncthreads();
    if (t < 8) hist[blockIdx.x * 8 + t] = scnt[t];
}

// ---------------------------------------------------------------------------
// scatter from histograms: zero global atomics, deterministic order
// (row-ascending within expert). Block 0 also writes cnt/off/tmap/tmap2/ntl.
// ---------------------------------------------------------------------------
__global__ __launch_bounds__(256) void scatter2_k(
        const int* __restrict__ idx, const int* __restrict__ hist,
        int* __restrict__ order, int* __restrict__ cnt, int* __restrict__ off,
        int* __restrict__ tmap, int* __restrict__ tmap2, int* __restrict__ ntl) {
    __shared__ int sbi[256];
    __shared__ int stot[8];
    __shared__ int sbase[8];
    int b0 = blockIdx.x, t = threadIdx.x;
    int b = b0 * 256 + t;
    int mybi = idx[b];
    sbi[t] = mybi;
    if (t < 8) {
        int tot = 0, pre = 0;
        for (int bb = 0; bb < RB_; bb++) {
            int h = hist[bb * 8 + t];
            if (bb < b0) pre += h;
            tot += h;
        }
        stot[t] = tot;
        sbase[t] = pre;
    }
    __syncthreads();
    if (t < 8) {
        int o = 0;
        for (int j = 0; j < t; j++) o += stot[j];
        sbase[t] += o;
    }
    __syncthreads();
    int rank = 0;
    for (int i = 0; i < 256; i++) {
        int v = sbi[i];
        rank += (i < t && v == mybi) ? 1 : 0;
    }
    order[sbase[mybi] + rank] = (mybi << 16) | b;

    if (b0 == 0 && t == 0) {
        int s = 0;
        for (int e = 0; e < E_; e++) { cnt[e] = stot[e]; off[e] = s; s += stot[e]; }
        int nt = 0;
        for (int e = 0; e < E_; e++)
            for (int t0 = 0; t0 < stot[e]; t0 += 64)
                tmap[nt++] = (e << 16) | t0;
        ntl[0] = nt;
        int nt2 = 0;
        for (int e = 0; e < E_; e++)
            for (int t0 = 0; t0 < stot[e]; t0 += 16)
                tmap2[nt2++] = (e << 16) | t0;
        ntl[1] = nt2;
    }
}

// ---------------------------------------------------------------------------
// GEMM1 via bf16x2-split MFMA (hh, lh, hl, ll), fp32 AGPR acc.
// Grid (KS, NTMAX): blockIdx.x = K-slice s fastest -> slice s pins to XCD s.
// Weight staging via global_load_lds DMA from the chunk-tiled Whi/Wlo format.
// MODE=1: plain stores to per-slice partials; MODE=0: atomicAdd fallback.
// (Round-9 body verbatim: no completion logic — r11's split-K threadfence
// variant serialized 6x and is retired.)
// ---------------------------------------------------------------------------
template<int MODE>
__global__ __launch_bounds__(256, 3) void gemm1_t(
        const float* __restrict__ x, const unsigned short* __restrict__ Whi,
        const unsigned short* __restrict__ Wlo, const int* __restrict__ order,
        const int* __restrict__ cnt, const int* __restrict__ off,
        const int* __restrict__ tmap, const int* __restrict__ ntl,
        float* __restrict__ dst) {
    int tid = blockIdx.y;
    if (tid >= ntl[0]) return;
    int tm = tmap[tid];
    int e = tm >> 16, tile0 = tm & 0xFFFF;
    int ce = cnt[e];
    int s = blockIdx.x;

    __shared__ int rows[64];
    __shared__ unsigned short xs_hi[64 * 40];
    __shared__ unsigned short xs_lo[64 * 40];
    __shared__ unsigned short ws_hi[256 * 40];
    __shared__ unsigned short ws_lo[256 * 40];

    int t = threadIdx.x;
    if (t < 64) {
        int i = tile0 + t;
        rows[t] = (i < ce) ? (order[off[e] + i] & 0xFFFF) : -1;
    }
    __syncthreads();
    int xrow0 = rows[0];

    int lane = t & 63, w = t >> 6;
    int lr = lane & 15, quad = lane >> 4;
    int kbase = s * KSEG_;
    int wuni = t & ~63;       // wave-uniform lane-0 thread index

    f32x4 acc[4][4];
    #pragma unroll
    for (int mt = 0; mt < 4; mt++)
        #pragma unroll
        for (int nt = 0; nt < 4; nt++)
            acc[mt][nt] = (f32x4){0.f, 0.f, 0.f, 0.f};

    for (int kb = 0; kb < KSEG_; kb += 32) {
        // ---- weight staging: async DMA of the 20480B chunk blocks ----
        {
            int ci = (kbase + kb) >> 5;
            const unsigned short* ph = Whi + ((size_t)e * NCH_ + ci) * CHW_;
            const unsigned short* pl = Wlo + ((size_t)e * NCH_ + ci) * CHW_;
            #pragma unroll
            for (int j = 0; j < 5; j++) {
                GLOAD_LDS16(ph + ((size_t)(j * 256 + t)) * 8,
                            ws_hi + (size_t)(j * 256 + wuni) * 8);
                GLOAD_LDS16(pl + ((size_t)(j * 256 + t)) * 8,
                            ws_lo + (size_t)(j * 256 + wuni) * 8);
            }
        }
        // ---- x staging: load + hi/lo split (VALU, overlaps the DMA) ----
        #pragma unroll
        for (int it = 0; it < 2; it++) {
            int i = t + it * 256;
            int rr = i >> 3, sg = i & 7;
            int row = rows[rr];
            if (row < 0) row = xrow0;
            float4 v = *(const float4*)(x + (size_t)row * D_ + kbase + kb + sg * 4);
            unsigned short h4[4], l4[4];
            float vv[4] = {v.x, v.y, v.z, v.w};
            #pragma unroll
            for (int j = 0; j < 4; j++) {
                unsigned short hi = bf16_rne(vv[j]);
                h4[j] = hi;
                l4[j] = bf16_rne(vv[j] - bf16_f(hi));
            }
            *(ush4*)&xs_hi[rr * 40 + sg * 4] = *(const ush4*)h4;
            *(ush4*)&xs_lo[rr * 40 + sg * 4] = *(const ush4*)l4;
        }
        __syncthreads();

        bf16x8 ah[4], al[4], bh[4], bl[4];
        #pragma unroll
        for (int mt = 0; mt < 4; mt++) {
            ah[mt] = __builtin_bit_cast(bf16x8, *(const ush8*)&xs_hi[(mt * 16 + lr) * 40 + quad * 8]);
            al[mt] = __builtin_bit_cast(bf16x8, *(const ush8*)&xs_lo[(mt * 16 + lr) * 40 + quad * 8]);
        }
        #pragma unroll
        for (int nt = 0; nt < 4; nt++) {
            int col = w * 64 + nt * 16 + lr;
            bh[nt] = __builtin_bit_cast(bf16x8, *(const ush8*)&ws_hi[col * 40 + quad * 8]);
            bl[nt] = __builtin_bit_cast(bf16x8, *(const ush8*)&ws_lo[col * 40 + quad * 8]);
        }
        #pragma unroll
        for (int mt = 0; mt < 4; mt++)
            #pragma unroll
            for (int nt = 0; nt < 4; nt++) {
                acc[mt][nt] = __builtin_amdgcn_mfma_f32_16x16x32_bf16(ah[mt], bh[nt], acc[mt][nt], 0, 0, 0);
                acc[mt][nt] = __builtin_amdgcn_mfma_f32_16x16x32_bf16(al[mt], bh[nt], acc[mt][nt], 0, 0, 0);
                acc[mt][nt] = __builtin_amdgcn_mfma_f32_16x16x32_bf16(ah[mt], bl[nt], acc[mt][nt], 0, 0, 0);
                acc[mt][nt] = __builtin_amdgcn_mfma_f32_16x16x32_bf16(al[mt], bl[nt], acc[mt][nt], 0, 0, 0);
            }
        __syncthreads();
    }

    size_t p0 = (size_t)off[e] + tile0;
    if (MODE == 1) {
        float* dp = dst + ((size_t)s * B_ + p0) * H_;
        #pragma unroll
        for (int mt = 0; mt < 4; mt++) {
            int rl = mt * 16 + quad * 4;
            #pragma unroll
            for (int nt = 0; nt < 4; nt++) {
                int col = w * 64 + nt * 16 + lr;
                #pragma unroll
                for (int rg = 0; rg < 4; rg++) {
                    if (tile0 + rl + rg < ce)
                        dp[(size_t)(rl + rg) * H_ + col] = acc[mt][nt][rg];
                }
            }
        }
    } else {
        #pragma unroll
        for (int mt = 0; mt < 4; mt++) {
            int rl = mt * 16 + quad * 4;
            #pragma unroll
            for (int nt = 0; nt < 4; nt++) {
                int col = w * 64 + nt * 16 + lr;
                #pragma unroll
                for (int rg = 0; rg < 4; rg++) {
                    if (tile0 + rl + rg < ce)
                        atomicAdd(&dst[(p0 + rl + rg) * H_ + col], acc[mt][nt][rg]);
                }
            }
        }
    }
}

// ---------------------------------------------------------------------------
// bias + exact GELU, in place on hws (fp32) — legacy fallback path
// ---------------------------------------------------------------------------
__global__ __launch_bounds__(256) void bias_gelu_k(
        float* __restrict__ hws, const float* __restrict__ B1b,
        const int* __restrict__ order) {
    int gid = blockIdx.x * 256 + threadIdx.x;
    int p = gid >> 6, c4 = (gid & 63) * 4;
    int e = order[p] >> 16;
    float4 v = *(const float4*)(hws + (size_t)p * H_ + c4);
    const float4 bb = *(const float4*)(B1b + e * H_ + c4);
    float pre[4] = {v.x + bb.x, v.y + bb.y, v.z + bb.z, v.w + bb.w};
    float4 o;
    o.x = 0.5f * pre[0] * (1.0f + erff(pre[0] * 0.70710678118654752440f));
    o.y = 0.5f * pre[1] * (1.0f + erff(pre[1] * 0.70710678118654752440f));
    o.z = 0.5f * pre[2] * (1.0f + erff(pre[2] * 0.70710678118654752440f));
    o.w = 0.5f * pre[3] * (1.0f + erff(pre[3] * 0.70710678118654752440f));
    *(float4*)(hws + (size_t)p * H_ + c4) = o;
}

// ---------------------------------------------------------------------------
// GEMM2, 16-row tiles, 4 waves K-split over H, LDS cross-wave reduce.
// FUSE=1: A = gelu(sum_s hpart + b1) inline; FUSE=0: A = hws (post-GELU).
// ---------------------------------------------------------------------------
template<int FUSE>
__global__ __launch_bounds__(256) void gemm2_t(
        const float* __restrict__ hsrc,
        const unsigned short* __restrict__ W2thi, const unsigned short* __restrict__ W2tlo,
        const float* __restrict__ B1b, const float* __restrict__ B2b,
        const int* __restrict__ order, const int* __restrict__ cnt,
        const int* __restrict__ off, const int* __restrict__ tmap2,
        const int* __restrict__ ntl, float* __restrict__ out) {
    int tid = blockIdx.x;
    if (tid >= ntl[1]) return;
    int tm = tmap2[tid];
    int e = tm >> 16, tile0 = tm & 0xFFFF;
    int ce = cnt[e];

    __shared__ int rows[16];
    __shared__ float red[3][64][28];

    int t = threadIdx.x;
    if (t < 16) {
        int i = tile0 + t;
        rows[t] = (i < ce) ? (order[off[e] + i] & 0xFFFF) : -1;
    }
    __syncthreads();

    int lane = t & 63, w = t >> 6;
    int m = lane & 15, q = lane >> 4;
    int p = off[e] + tile0 + ((tile0 + m < ce) ? m : 0);

    f32x4 acc[7];
    #pragma unroll
    for (int nt = 0; nt < 7; nt++) acc[nt] = (f32x4){0.f, 0.f, 0.f, 0.f};

    const unsigned short* w2h = W2thi + (size_t)e * C_ * H_;
    const unsigned short* w2l = W2tlo + (size_t)e * C_ * H_;

    #pragma unroll
    for (int si = 0; si < 2; si++) {
        int s = w * 2 + si;
        int k0 = s * 32 + q * 8;
        size_t o = (size_t)p * H_ + k0;
        float f[8];
        if (FUSE) {
            float4 a0 = *(const float4*)(hsrc + o);
            float4 a1 = *(const float4*)(hsrc + o + 4);
            #pragma unroll
            for (int s2 = 1; s2 < KS_; s2++) {
                const float* sp = hsrc + (size_t)s2 * B_ * H_ + o;
                float4 b0 = *(const float4*)sp;
                float4 b1v = *(const float4*)(sp + 4);
                a0.x += b0.x; a0.y += b0.y; a0.z += b0.z; a0.w += b0.w;
                a1.x += b1v.x; a1.y += b1v.y; a1.z += b1v.z; a1.w += b1v.w;
            }
            float4 bb0 = *(const float4*)(B1b + e * H_ + k0);
            float4 bb1 = *(const float4*)(B1b + e * H_ + k0 + 4);
            float pre[8] = {a0.x + bb0.x, a0.y + bb0.y, a0.z + bb0.z, a0.w + bb0.w,
                            a1.x + bb1.x, a1.y + bb1.y, a1.z + bb1.z, a1.w + bb1.w};
            #pragma unroll
            for (int j = 0; j < 8; j++)
                f[j] = 0.5f * pre[j] * (1.0f + erff(pre[j] * 0.70710678118654752440f));
        } else {
            float4 v0 = *(const float4*)(hsrc + o);
            float4 v1 = *(const float4*)(hsrc + o + 4);
            f[0] = v0.x; f[1] = v0.y; f[2] = v0.z; f[3] = v0.w;
            f[4] = v1.x; f[5] = v1.y; f[6] = v1.z; f[7] = v1.w;
        }
        unsigned short hh[8], lo[8];
        #pragma unroll
        for (int j = 0; j < 8; j++) {
            unsigned short hi = bf16_rne(f[j]);
            hh[j] = hi;
            lo[j] = bf16_rne(f[j] - bf16_f(hi));
        }
        bf16x8 ah = __builtin_bit_cast(bf16x8, *(const ush8*)hh);
        bf16x8 al = __builtin_bit_cast(bf16x8, *(const ush8*)lo);
        #pragma unroll
        for (int nt = 0; nt < 7; nt++) {
            // cols >= C_ read past the unpadded plane into adjacent ws arrays;
            // results land in discarded lanes only.
            size_t bo = (size_t)(nt * 16 + m) * H_ + k0;
            bf16x8 bh = __builtin_bit_cast(bf16x8, *(const ush8*)(w2h + bo));
            bf16x8 bl = __builtin_bit_cast(bf16x8, *(const ush8*)(w2l + bo));
            acc[nt] = __builtin_amdgcn_mfma_f32_16x16x32_bf16(ah, bh, acc[nt], 0, 0, 0);
            acc[nt] = __builtin_amdgcn_mfma_f32_16x16x32_bf16(al, bh, acc[nt], 0, 0, 0);
            acc[nt] = __builtin_amdgcn_mfma_f32_16x16x32_bf16(ah, bl, acc[nt], 0, 0, 0);
            acc[nt] = __builtin_amdgcn_mfma_f32_16x16x32_bf16(al, bl, acc[nt], 0, 0, 0);
        }
    }

    if (w > 0) {
        #pragma unroll
        for (int nt = 0; nt < 7; nt++)
            #pragma unroll
            for (int i = 0; i < 4; i++)
                red[w - 1][lane][nt * 4 + i] = acc[nt][i];
    }
    __syncthreads();
    if (w == 0) {
        #pragma unroll
        for (int nt = 0; nt < 7; nt++)
            #pragma unroll
            for (int i = 0; i < 4; i++)
                acc[nt][i] = ((acc[nt][i] + red[0][lane][nt * 4 + i])
                              + red[1][lane][nt * 4 + i]) + red[2][lane][nt * 4 + i];
        #pragma unroll
        for (int nt = 0; nt < 7; nt++) {
            int c = nt * 16 + m;
            if (c >= C_) continue;
            float bias = B2b[e * C_ + c];
            #pragma unroll
            for (int i = 0; i < 4; i++) {
                int grow = q * 4 + i;
                if (tile0 + grow < ce)
                    out[(size_t)rows[grow] * C_ + c] = acc[nt][i] + bias;
            }
        }
    }
}

// ---------------------------------------------------------------------------
extern "C" void kernel_launch(void* const* d_in, const int* in_sizes, int n_in,
                              void* d_out, int out_size, void* d_ws, size_t ws_size,
                              hipStream_t stream) {
    const float* x        = (const float*)d_in[0];
    const float* coeffs   = (const float*)d_in[1];
    const float* router_w = (const float*)d_in[2];
    const float* router_b = (const float*)d_in[3];
    const float* w1       = (const float*)d_in[4];
    const float* b1       = (const float*)d_in[5];
    const float* w2       = (const float*)d_in[6];
    const float* b2       = (const float*)d_in[7];
    float* out = (float*)d_out;

    // workspace layout: weight planes chunk-tiled (E*NCH*CHW ushorts each)
    unsigned short* Whi   = (unsigned short*)d_ws;        // E*96*10240 ush (15.7MB)
    unsigned short* Wlo   = Whi + (size_t)E_ * NCH_ * CHW_;
    unsigned short* W2thi = Wlo + (size_t)E_ * NCH_ * CHW_;  // E*C*H ush
    unsigned short* W2tlo = W2thi + (size_t)E_ * C_ * H_;
    float* B1b  = (float*)(W2tlo + (size_t)E_ * C_ * H_); // E*H
    float* B2b  = B1b + (size_t)E_ * H_;                  // E*C
    int* order  = (int*)(B2b + E_ * C_);                  // B (packed e<<16|b)
    int* cnt    = order + B_;                             // 8
    int* off    = cnt + E_;                               // 8
    int* tmap   = off + E_;                               // NTMAX
    int* tmap2  = tmap + NTMAX_;                          // NT2MAX
    int* ntl    = tmap2 + NT2MAX_;                        // 4
    int* idx    = ntl + 4;                                // B ints
    int* hist   = idx + B_;                               // RB*8 = 256 ints
    float* hws  = (float*)(hist + 256);                   // B*H f32 (slice 0)
    // lpart (RKS*B*8 f64 = 8 MB) aliases hws slice 0 exactly; dead before
    // gemm1 (use_part) / before the hws memset (fallback).
    double* lpart = (double*)hws;

    size_t prefix_bytes = (size_t)((char*)hws - (char*)d_ws);
    int use_part = (ws_size >= prefix_bytes + (size_t)KS_ * B_ * H_ * sizeof(float) + 256) ? 1 : 0;

    // one fused launch: router + W1/W2 blends + b1/b2 blends (overlapped)
    mega_k<<<dim3(MEGA_TOT_), 256, 0, stream>>>(
        x, router_w, w1, w2, b1, b2, Whi, Wlo, W2thi, W2tlo, B1b, B2b,
        lpart, coeffs);

    argmax_hist_k<<<dim3(RB_), 256, 0, stream>>>(lpart, router_b, coeffs, idx, hist);
    scatter2_k<<<dim3(RB_), 256, 0, stream>>>(idx, hist, order, cnt, off,
                                              tmap, tmap2, ntl);

    if (use_part) {
        // no memset needed: every (s,p,h) partial is written by exactly one block
        gemm1_t<1><<<dim3(KS_, NTMAX_), 256, 0, stream>>>(x, Whi, Wlo, order, cnt,
                                                          off, tmap, ntl, hws);
        // fused: slice-reduce + b1 + GELU inside gemm2's A-staging
        gemm2_t<1><<<dim3(NT2MAX_), 256, 0, stream>>>(hws, W2thi, W2tlo, B1b, B2b,
                                                      order, cnt, off, tmap2, ntl, out);
    } else {
        // zero hws (lpart alias dead), atomic partial sums
        hipMemsetAsync(hws, 0, (size_t)B_ * H_ * sizeof(float), stream);
        gemm1_t<0><<<dim3(KS_, NTMAX_), 256, 0, stream>>>(x, Whi, Wlo, order, cnt,
                                                          off, tmap, ntl, hws);
        bias_gelu_k<<<dim3(B_ * H_ / 4 / 256), 256, 0, stream>>>(hws, B1b, order);
        gemm2_t<0><<<dim3(NT2MAX_), 256, 0, stream>>>(hws, W2thi, W2tlo, B1b, B2b,
                                                      order, cnt, off, tmap2, ntl, out);
    }
}

// Round 13
// 323.036 us; speedup vs baseline: 2.0241x; 1.0296x over previous
//
#include <hip/hip_runtime.h>
#include <math.h>

#define B_  8192
#define E_  8
#define D_  3072
#define H_  256
#define C_  100
#define DH_ (D_*H_)
#define HC_ (H_*C_)
#define KS_ 4            // K splits in gemm1 (r13: 8->4, halves reduce traffic)
#define KSEG_ (D_/KS_)   // 768
#define RKS_ 16          // K splits in router
#define RSEG_ (D_/RKS_)  // 192
#define RB_ (B_/256)     // 32 row-blocks of 256 rows
#define NTMAX_ 136       // max 64-row tiles over all experts (128+8 slack)
#define NT2MAX_ 528      // max 16-row tiles (512+16 slack)
#define NCH_ (D_/32)     // 96 32-k chunks
#define CHW_ 10240       // ushorts per weight chunk block: 256 cols * 40

// mega-kernel block ranges (router first: it's on the critical path)
#define MEGA_R_   (RB_*RKS_)          // 512 router blocks (4 waves x 64 rows)
#define MEGA_W1_  (E_*NCH_)           // 768 W1 chunk tiles (1 block per (e,ci))
#define MEGA_W2_  (C_*E_)             // 800 blendw2t columns
#define MEGA_BB_  3                   // b1/b2 blend blocks
#define MEGA_TOT_ (MEGA_R_ + MEGA_W1_ + MEGA_W2_ + MEGA_BB_)

typedef __attribute__((ext_vector_type(4))) float  f32x4;
typedef __attribute__((ext_vector_type(8))) __bf16 bf16x8;
typedef __attribute__((ext_vector_type(8))) unsigned short ush8;
typedef __attribute__((ext_vector_type(4))) unsigned short ush4;

// async global->LDS DMA, 16B per lane; lds dest = uniform base + lane*16
#define GLOAD_LDS16(g, l) __builtin_amdgcn_global_load_lds( \
    (const __attribute__((address_space(1))) void*)(g),     \
    (__attribute__((address_space(3))) void*)(l), 16, 0, 0)

__device__ inline unsigned short bf16_rne(float f) {
    unsigned u = __builtin_bit_cast(unsigned, f);
    unsigned r = (u + 0x7FFFu + ((u >> 16) & 1u)) >> 16;
    return (unsigned short)r;
}
__device__ inline float bf16_f(unsigned short h) {
    unsigned u = ((unsigned)h) << 16;
    return __builtin_bit_cast(float, u);
}

#define MISC_B1_ (E_*H_/4)            // 512 float4
#define MISC_B2_ (E_*C_/4)            // 200 float4

// ---------------------------------------------------------------------------
// MEGA kernel: router GEMV + W1/W2 blend-transpose + b1/b2 blends, one launch.
// Router = LDS-direct body (register prefetch RETIRED: spilled under default
// cap (r8) AND (256,2) (r10), +97MB scratch WRITE signature both times).
// Split-K completion also RETIRED (r11: __threadfence serialization, 6x).
// W1 blend: 1 block per (e, chunk): two fully-SEQUENTIAL 32KB reads (float4),
// LDS [32][256] transpose, chunk-tiled store (gemm1's DMA format).
// ---------------------------------------------------------------------------
__global__ __launch_bounds__(256) void mega_k(
        const float* __restrict__ x, const float* __restrict__ rw,
        const float* __restrict__ w1, const float* __restrict__ w2,
        const float* __restrict__ b1, const float* __restrict__ b2,
        unsigned short* __restrict__ Whi, unsigned short* __restrict__ Wlo,
        unsigned short* __restrict__ W2thi, unsigned short* __restrict__ W2tlo,
        float* __restrict__ B1b, float* __restrict__ B2b,
        double* __restrict__ lpart, const float* __restrict__ coeffs) {
    __shared__ char smem[36864];
    int bid = blockIdx.x;
    int t = threadIdx.x;

    if (bid < MEGA_R_) {
        // ---- router fp64 GEMV (LDS-direct staging, proven round-7/9 body) ----
        float  (*xs)[64][33] = (float(*)[64][33])smem;          // 33792 B
        double (*wls)[8]     = (double(*)[8])(smem + 33792);    // 2048 B
        int w = t >> 6, lane = t & 63;
        int rowblk = (bid & (RB_ - 1)) * 256;
        int s2     = bid >> 5;                 // K-slice
        int kbase  = s2 * RSEG_;
        int row0   = rowblk + w * 64;
        double c0 = (double)coeffs[0], c1 = (double)coeffs[1];

        double acc[8] = {0, 0, 0, 0, 0, 0, 0, 0};

        for (int kb = 0; kb < RSEG_; kb += 32) {
            #pragma unroll
            for (int it = 0; it < 8; it++) {
                int i = lane + it * 64;
                int r = i >> 3, c4 = i & 7;
                *(float4*)&xs[w][r][c4 * 4] =
                    *(const float4*)(x + (size_t)(row0 + r) * D_ + kbase + kb + c4 * 4);
            }
            if (w == 0) {
                #pragma unroll
                for (int it = 0; it < 4; it++) {
                    int i = lane + it * 64;
                    int k = i >> 3, ee = i & 7;
                    wls[k][ee] = c0 * (double)rw[(size_t)(kbase + kb + k) * 8 + ee]
                               + c1 * (double)rw[(size_t)(D_ + kbase + kb + k) * 8 + ee];
                }
            }
            __syncthreads();
            #pragma unroll
            for (int kk = 0; kk < 32; kk++) {
                double xv = (double)xs[w][lane][kk];
                double2 w01 = *(const double2*)&wls[kk][0];
                double2 w23 = *(const double2*)&wls[kk][2];
                double2 w45 = *(const double2*)&wls[kk][4];
                double2 w67 = *(const double2*)&wls[kk][6];
                acc[0] = fma(xv, w01.x, acc[0]);
                acc[1] = fma(xv, w01.y, acc[1]);
                acc[2] = fma(xv, w23.x, acc[2]);
                acc[3] = fma(xv, w23.y, acc[3]);
                acc[4] = fma(xv, w45.x, acc[4]);
                acc[5] = fma(xv, w45.y, acc[5]);
                acc[6] = fma(xv, w67.x, acc[6]);
                acc[7] = fma(xv, w67.y, acc[7]);
            }
            __syncthreads();
        }
        size_t base = ((size_t)s2 * B_ + row0 + lane) * 8;
        #pragma unroll
        for (int ee = 0; ee < 8; ee++) lpart[base + ee] = acc[ee];

    } else if (bid < MEGA_R_ + MEGA_W1_) {
        // ---- W1 blend: sequential 32KB reads, transpose, chunk-tiled store ----
        int lid = bid - MEGA_R_;
        int e  = lid / NCH_;
        int ci = lid - e * NCH_;
        int d0 = ci * 32;
        unsigned short* thi = (unsigned short*)smem;        // [32][256] = 16KB
        unsigned short* tlo = thi + 32 * 256;               // +16KB
        float c0 = coeffs[0], c1 = coeffs[1];
        const float* pa = w1 + ((size_t)(e * 2 + 0) * D_ + d0) * H_;
        const float* pb = w1 + ((size_t)(e * 2 + 1) * D_ + d0) * H_;
        #pragma unroll
        for (int it = 0; it < 8; it++) {
            int i4 = t + it * 256;                // 2048 float4 = 32d x 256h
            float4 va = *(const float4*)(pa + (size_t)i4 * 4);
            float4 vb = *(const float4*)(pb + (size_t)i4 * 4);
            float vv[4] = {c0 * va.x + c1 * vb.x, c0 * va.y + c1 * vb.y,
                           c0 * va.z + c1 * vb.z, c0 * va.w + c1 * vb.w};
            unsigned short h4[4], l4[4];
            #pragma unroll
            for (int j = 0; j < 4; j++) {
                unsigned short hi = bf16_rne(vv[j]);
                h4[j] = hi;
                l4[j] = bf16_rne(vv[j] - bf16_f(hi));
            }
            *(ush4*)&thi[i4 * 4] = *(const ush4*)h4;   // linear [d][h]
            *(ush4*)&tlo[i4 * 4] = *(const ush4*)l4;
        }
        __syncthreads();
        #pragma unroll
        for (int it = 0; it < 4; it++) {
            int j = t + it * 256;                 // 1024 ush8 = 256h x 4(d8)
            int h = j >> 2, d8 = (j & 3) * 8;
            unsigned short vh[8], vl[8];
            #pragma unroll
            for (int k2 = 0; k2 < 8; k2++) {
                vh[k2] = thi[(d8 + k2) * 256 + h];
                vl[k2] = tlo[(d8 + k2) * 256 + h];
            }
            size_t g = ((size_t)e * NCH_ + ci) * CHW_ + (size_t)h * 40 + d8;
            *(ush8*)(Whi + g) = *(const ush8*)vh;
            *(ush8*)(Wlo + g) = *(const ush8*)vl;
        }

    } else if (bid < MEGA_R_ + MEGA_W1_ + MEGA_W2_) {
        // ---- W2 blend + hi/lo split + transpose to [e][c][k] ----
        int lid = bid - (MEGA_R_ + MEGA_W1_);
        int c = lid % C_, e = lid / C_;
        int k = t;
        float c0 = coeffs[0], c1 = coeffs[1];
        float v = c0 * w2[((size_t)(e * 2 + 0) * H_ + k) * C_ + c]
                + c1 * w2[((size_t)(e * 2 + 1) * H_ + k) * C_ + c];
        unsigned short hi = bf16_rne(v);
        W2thi[(size_t)(e * C_ + c) * H_ + k] = hi;
        W2tlo[(size_t)(e * C_ + c) * H_ + k] = bf16_rne(v - bf16_f(hi));

    } else {
        // ---- b1 / b2 blends ----
        int gid = (bid - (MEGA_R_ + MEGA_W1_ + MEGA_W2_)) * 256 + t;
        float c0 = coeffs[0], c1 = coeffs[1];
        if (gid < MISC_B1_) {
            const float4* p = (const float4*)b1;
            int e = gid / (H_ / 4), r = gid - e * (H_ / 4);
            float4 a = p[(e * 2 + 0) * (H_ / 4) + r];
            float4 bq = p[(e * 2 + 1) * (H_ / 4) + r];
            float4 o;
            o.x = c0 * a.x + c1 * bq.x;
            o.y = c0 * a.y + c1 * bq.y;
            o.z = c0 * a.z + c1 * bq.z;
            o.w = c0 * a.w + c1 * bq.w;
            ((float4*)B1b)[gid] = o;
        } else if (gid < MISC_B1_ + MISC_B2_) {
            int g2 = gid - MISC_B1_;
            const float4* p = (const float4*)b2;
            int e = g2 / (C_ / 4), r = g2 - e * (C_ / 4);
            float4 a = p[(e * 2 + 0) * (C_ / 4) + r];
            float4 bq = p[(e * 2 + 1) * (C_ / 4) + r];
            float4 o;
            o.x = c0 * a.x + c1 * bq.x;
            o.y = c0 * a.y + c1 * bq.y;
            o.z = c0 * a.z + c1 * bq.z;
            o.w = c0 * a.w + c1 * bq.w;
            ((float4*)B2b)[g2] = o;
        }
    }
}

// ---------------------------------------------------------------------------
// argmax + per-block histogram. fp64, strict > (np first-max), coalesced
// double2 row reads. No global atomics.
// ---------------------------------------------------------------------------
__global__ __launch_bounds__(256) void argmax_hist_k(
        const double* __restrict__ lpart, const float* __restrict__ rb,
        const float* __restrict__ coeffs, int* __restrict__ idx,
        int* __restrict__ hist) {
    __shared__ int scnt[8];
    int t = threadIdx.x;
    if (t < 8) scnt[t] = 0;
    __syncthreads();
    int b = blockIdx.x * 256 + t;
    double c0 = (double)coeffs[0], c1 = (double)coeffs[1];
    double l[8];
    #pragma unroll
    for (int e = 0; e < 8; e++)
        l[e] = c0 * (double)rb[e] + c1 * (double)rb[8 + e];
    for (int s2 = 0; s2 < RKS_; s2++) {
        const double2* pp = (const double2*)(lpart + ((size_t)s2 * B_ + b) * 8);
        double2 v0 = pp[0], v1 = pp[1], v2 = pp[2], v3 = pp[3];
        l[0] += v0.x; l[1] += v0.y; l[2] += v1.x; l[3] += v1.y;
        l[4] += v2.x; l[5] += v2.y; l[6] += v3.x; l[7] += v3.y;
    }
    double best = -1e300;
    int bi = 0;
    #pragma unroll
    for (int e = 0; e < 8; e++)
        if (l[e] > best) { best = l[e]; bi = e; }
    idx[b] = bi;
    atomicAdd(&scnt[bi], 1);       // LDS atomic only
    __syncthreads();
    if (t < 8) hist[blockIdx.x * 8 + t] = scnt[t];
}

// ---------------------------------------------------------------------------
// scatter from histograms: zero global atomics, deterministic order
// (row-ascending within expert). Block 0 also writes cnt/off/tmap/tmap2/ntl.
// ---------------------------------------------------------------------------
__global__ __launch_bounds__(256) void scatter2_k(
        const int* __restrict__ idx, const int* __restrict__ hist,
        int* __restrict__ order, int* __restrict__ cnt, int* __restrict__ off,
        int* __restrict__ tmap, int* __restrict__ tmap2, int* __restrict__ ntl) {
    __shared__ int sbi[256];
    __shared__ int stot[8];
    __shared__ int sbase[8];
    int b0 = blockIdx.x, t = threadIdx.x;
    int b = b0 * 256 + t;
    int mybi = idx[b];
    sbi[t] = mybi;
    if (t < 8) {
        int tot = 0, pre = 0;
        for (int bb = 0; bb < RB_; bb++) {
            int h = hist[bb * 8 + t];
            if (bb < b0) pre += h;
            tot += h;
        }
        stot[t] = tot;
        sbase[t] = pre;
    }
    __syncthreads();
    if (t < 8) {
        int o = 0;
        for (int j = 0; j < t; j++) o += stot[j];
        sbase[t] += o;
    }
    __syncthreads();
    int rank = 0;
    for (int i = 0; i < 256; i++) {
        int v = sbi[i];
        rank += (i < t && v == mybi) ? 1 : 0;
    }
    order[sbase[mybi] + rank] = (mybi << 16) | b;

    if (b0 == 0 && t == 0) {
        int s = 0;
        for (int e = 0; e < E_; e++) { cnt[e] = stot[e]; off[e] = s; s += stot[e]; }
        int nt = 0;
        for (int e = 0; e < E_; e++)
            for (int t0 = 0; t0 < stot[e]; t0 += 64)
                tmap[nt++] = (e << 16) | t0;
        ntl[0] = nt;
        int nt2 = 0;
        for (int e = 0; e < E_; e++)
            for (int t0 = 0; t0 < stot[e]; t0 += 16)
                tmap2[nt2++] = (e << 16) | t0;
        ntl[1] = nt2;
    }
}

// ---------------------------------------------------------------------------
// GEMM1 via bf16x2-split MFMA (hh, lh, hl, ll), fp32 AGPR acc.
// Grid (KS=4, NTMAX): wgid = s + 4*tile -> slice s lands on XCDs {s, s+4}.
// Per-XCD weight working set 6.3MB (> 4MB L2, spills to L3 — watch FETCH).
// Weight staging via global_load_lds DMA from the chunk-tiled Whi/Wlo format.
// MODE=1: plain stores to per-slice partials; MODE=0: atomicAdd fallback.
// ---------------------------------------------------------------------------
template<int MODE>
__global__ __launch_bounds__(256, 3) void gemm1_t(
        const float* __restrict__ x, const unsigned short* __restrict__ Whi,
        const unsigned short* __restrict__ Wlo, const int* __restrict__ order,
        const int* __restrict__ cnt, const int* __restrict__ off,
        const int* __restrict__ tmap, const int* __restrict__ ntl,
        float* __restrict__ dst) {
    int tid = blockIdx.y;
    if (tid >= ntl[0]) return;
    int tm = tmap[tid];
    int e = tm >> 16, tile0 = tm & 0xFFFF;
    int ce = cnt[e];
    int s = blockIdx.x;

    __shared__ int rows[64];
    __shared__ unsigned short xs_hi[64 * 40];
    __shared__ unsigned short xs_lo[64 * 40];
    __shared__ unsigned short ws_hi[256 * 40];
    __shared__ unsigned short ws_lo[256 * 40];

    int t = threadIdx.x;
    if (t < 64) {
        int i = tile0 + t;
        rows[t] = (i < ce) ? (order[off[e] + i] & 0xFFFF) : -1;
    }
    __syncthreads();
    int xrow0 = rows[0];

    int lane = t & 63, w = t >> 6;
    int lr = lane & 15, quad = lane >> 4;
    int kbase = s * KSEG_;
    int wuni = t & ~63;       // wave-uniform lane-0 thread index

    f32x4 acc[4][4];
    #pragma unroll
    for (int mt = 0; mt < 4; mt++)
        #pragma unroll
        for (int nt = 0; nt < 4; nt++)
            acc[mt][nt] = (f32x4){0.f, 0.f, 0.f, 0.f};

    for (int kb = 0; kb < KSEG_; kb += 32) {
        // ---- weight staging: async DMA of the 20480B chunk blocks ----
        {
            int ci = (kbase + kb) >> 5;
            const unsigned short* ph = Whi + ((size_t)e * NCH_ + ci) * CHW_;
            const unsigned short* pl = Wlo + ((size_t)e * NCH_ + ci) * CHW_;
            #pragma unroll
            for (int j = 0; j < 5; j++) {
                GLOAD_LDS16(ph + ((size_t)(j * 256 + t)) * 8,
                            ws_hi + (size_t)(j * 256 + wuni) * 8);
                GLOAD_LDS16(pl + ((size_t)(j * 256 + t)) * 8,
                            ws_lo + (size_t)(j * 256 + wuni) * 8);
            }
        }
        // ---- x staging: load + hi/lo split (VALU, overlaps the DMA) ----
        #pragma unroll
        for (int it = 0; it < 2; it++) {
            int i = t + it * 256;
            int rr = i >> 3, sg = i & 7;
            int row = rows[rr];
            if (row < 0) row = xrow0;
            float4 v = *(const float4*)(x + (size_t)row * D_ + kbase + kb + sg * 4);
            unsigned short h4[4], l4[4];
            float vv[4] = {v.x, v.y, v.z, v.w};
            #pragma unroll
            for (int j = 0; j < 4; j++) {
                unsigned short hi = bf16_rne(vv[j]);
                h4[j] = hi;
                l4[j] = bf16_rne(vv[j] - bf16_f(hi));
            }
            *(ush4*)&xs_hi[rr * 40 + sg * 4] = *(const ush4*)h4;
            *(ush4*)&xs_lo[rr * 40 + sg * 4] = *(const ush4*)l4;
        }
        __syncthreads();

        bf16x8 ah[4], al[4], bh[4], bl[4];
        #pragma unroll
        for (int mt = 0; mt < 4; mt++) {
            ah[mt] = __builtin_bit_cast(bf16x8, *(const ush8*)&xs_hi[(mt * 16 + lr) * 40 + quad * 8]);
            al[mt] = __builtin_bit_cast(bf16x8, *(const ush8*)&xs_lo[(mt * 16 + lr) * 40 + quad * 8]);
        }
        #pragma unroll
        for (int nt = 0; nt < 4; nt++) {
            int col = w * 64 + nt * 16 + lr;
            bh[nt] = __builtin_bit_cast(bf16x8, *(const ush8*)&ws_hi[col * 40 + quad * 8]);
            bl[nt] = __builtin_bit_cast(bf16x8, *(const ush8*)&ws_lo[col * 40 + quad * 8]);
        }
        #pragma unroll
        for (int mt = 0; mt < 4; mt++)
            #pragma unroll
            for (int nt = 0; nt < 4; nt++) {
                acc[mt][nt] = __builtin_amdgcn_mfma_f32_16x16x32_bf16(ah[mt], bh[nt], acc[mt][nt], 0, 0, 0);
                acc[mt][nt] = __builtin_amdgcn_mfma_f32_16x16x32_bf16(al[mt], bh[nt], acc[mt][nt], 0, 0, 0);
                acc[mt][nt] = __builtin_amdgcn_mfma_f32_16x16x32_bf16(ah[mt], bl[nt], acc[mt][nt], 0, 0, 0);
                acc[mt][nt] = __builtin_amdgcn_mfma_f32_16x16x32_bf16(al[mt], bl[nt], acc[mt][nt], 0, 0, 0);
            }
        __syncthreads();
    }

    size_t p0 = (size_t)off[e] + tile0;
    if (MODE == 1) {
        float* dp = dst + ((size_t)s * B_ + p0) * H_;
        #pragma unroll
        for (int mt = 0; mt < 4; mt++) {
            int rl = mt * 16 + quad * 4;
            #pragma unroll
            for (int nt = 0; nt < 4; nt++) {
                int col = w * 64 + nt * 16 + lr;
                #pragma unroll
                for (int rg = 0; rg < 4; rg++) {
                    if (tile0 + rl + rg < ce)
                        dp[(size_t)(rl + rg) * H_ + col] = acc[mt][nt][rg];
                }
            }
        }
    } else {
        #pragma unroll
        for (int mt = 0; mt < 4; mt++) {
            int rl = mt * 16 + quad * 4;
            #pragma unroll
            for (int nt = 0; nt < 4; nt++) {
                int col = w * 64 + nt * 16 + lr;
                #pragma unroll
                for (int rg = 0; rg < 4; rg++) {
                    if (tile0 + rl + rg < ce)
                        atomicAdd(&dst[(p0 + rl + rg) * H_ + col], acc[mt][nt][rg]);
                }
            }
        }
    }
}

// ---------------------------------------------------------------------------
// bias + exact GELU, in place on hws (fp32) — legacy fallback path
// ---------------------------------------------------------------------------
__global__ __launch_bounds__(256) void bias_gelu_k(
        float* __restrict__ hws, const float* __restrict__ B1b,
        const int* __restrict__ order) {
    int gid = blockIdx.x * 256 + threadIdx.x;
    int p = gid >> 6, c4 = (gid & 63) * 4;
    int e = order[p] >> 16;
    float4 v = *(const float4*)(hws + (size_t)p * H_ + c4);
    const float4 bb = *(const float4*)(B1b + e * H_ + c4);
    float pre[4] = {v.x + bb.x, v.y + bb.y, v.z + bb.z, v.w + bb.w};
    float4 o;
    o.x = 0.5f * pre[0] * (1.0f + erff(pre[0] * 0.70710678118654752440f));
    o.y = 0.5f * pre[1] * (1.0f + erff(pre[1] * 0.70710678118654752440f));
    o.z = 0.5f * pre[2] * (1.0f + erff(pre[2] * 0.70710678118654752440f));
    o.w = 0.5f * pre[3] * (1.0f + erff(pre[3] * 0.70710678118654752440f));
    *(float4*)(hws + (size_t)p * H_ + c4) = o;
}

// ---------------------------------------------------------------------------
// GEMM2, 16-row tiles, 4 waves K-split over H, LDS cross-wave reduce.
// FUSE=1: A = gelu(sum_s hpart + b1) inline (now only KS_=4 slices);
// FUSE=0: A = hws (post-GELU).
// ---------------------------------------------------------------------------
template<int FUSE>
__global__ __launch_bounds__(256) void gemm2_t(
        const float* __restrict__ hsrc,
        const unsigned short* __restrict__ W2thi, const unsigned short* __restrict__ W2tlo,
        const float* __restrict__ B1b, const float* __restrict__ B2b,
        const int* __restrict__ order, const int* __restrict__ cnt,
        const int* __restrict__ off, const int* __restrict__ tmap2,
        const int* __restrict__ ntl, float* __restrict__ out) {
    int tid = blockIdx.x;
    if (tid >= ntl[1]) return;
    int tm = tmap2[tid];
    int e = tm >> 16, tile0 = tm & 0xFFFF;
    int ce = cnt[e];

    __shared__ int rows[16];
    __shared__ float red[3][64][28];

    int t = threadIdx.x;
    if (t < 16) {
        int i = tile0 + t;
        rows[t] = (i < ce) ? (order[off[e] + i] & 0xFFFF) : -1;
    }
    __syncthreads();

    int lane = t & 63, w = t >> 6;
    int m = lane & 15, q = lane >> 4;
    int p = off[e] + tile0 + ((tile0 + m < ce) ? m : 0);

    f32x4 acc[7];
    #pragma unroll
    for (int nt = 0; nt < 7; nt++) acc[nt] = (f32x4){0.f, 0.f, 0.f, 0.f};

    const unsigned short* w2h = W2thi + (size_t)e * C_ * H_;
    const unsigned short* w2l = W2tlo + (size_t)e * C_ * H_;

    #pragma unroll
    for (int si = 0; si < 2; si++) {
        int s = w * 2 + si;
        int k0 = s * 32 + q * 8;
        size_t o = (size_t)p * H_ + k0;
        float f[8];
        if (FUSE) {
            float4 a0 = *(const float4*)(hsrc + o);
            float4 a1 = *(const float4*)(hsrc + o + 4);
            #pragma unroll
            for (int s2 = 1; s2 < KS_; s2++) {
                const float* sp = hsrc + (size_t)s2 * B_ * H_ + o;
                float4 b0 = *(const float4*)sp;
                float4 b1v = *(const float4*)(sp + 4);
                a0.x += b0.x; a0.y += b0.y; a0.z += b0.z; a0.w += b0.w;
                a1.x += b1v.x; a1.y += b1v.y; a1.z += b1v.z; a1.w += b1v.w;
            }
            float4 bb0 = *(const float4*)(B1b + e * H_ + k0);
            float4 bb1 = *(const float4*)(B1b + e * H_ + k0 + 4);
            float pre[8] = {a0.x + bb0.x, a0.y + bb0.y, a0.z + bb0.z, a0.w + bb0.w,
                            a1.x + bb1.x, a1.y + bb1.y, a1.z + bb1.z, a1.w + bb1.w};
            #pragma unroll
            for (int j = 0; j < 8; j++)
                f[j] = 0.5f * pre[j] * (1.0f + erff(pre[j] * 0.70710678118654752440f));
        } else {
            float4 v0 = *(const float4*)(hsrc + o);
            float4 v1 = *(const float4*)(hsrc + o + 4);
            f[0] = v0.x; f[1] = v0.y; f[2] = v0.z; f[3] = v0.w;
            f[4] = v1.x; f[5] = v1.y; f[6] = v1.z; f[7] = v1.w;
        }
        unsigned short hh[8], lo[8];
        #pragma unroll
        for (int j = 0; j < 8; j++) {
            unsigned short hi = bf16_rne(f[j]);
            hh[j] = hi;
            lo[j] = bf16_rne(f[j] - bf16_f(hi));
        }
        bf16x8 ah = __builtin_bit_cast(bf16x8, *(const ush8*)hh);
        bf16x8 al = __builtin_bit_cast(bf16x8, *(const ush8*)lo);
        #pragma unroll
        for (int nt = 0; nt < 7; nt++) {
            // cols >= C_ read past the unpadded plane into adjacent ws arrays;
            // results land in discarded lanes only.
            size_t bo = (size_t)(nt * 16 + m) * H_ + k0;
            bf16x8 bh = __builtin_bit_cast(bf16x8, *(const ush8*)(w2h + bo));
            bf16x8 bl = __builtin_bit_cast(bf16x8, *(const ush8*)(w2l + bo));
            acc[nt] = __builtin_amdgcn_mfma_f32_16x16x32_bf16(ah, bh, acc[nt], 0, 0, 0);
            acc[nt] = __builtin_amdgcn_mfma_f32_16x16x32_bf16(al, bh, acc[nt], 0, 0, 0);
            acc[nt] = __builtin_amdgcn_mfma_f32_16x16x32_bf16(ah, bl, acc[nt], 0, 0, 0);
            acc[nt] = __builtin_amdgcn_mfma_f32_16x16x32_bf16(al, bl, acc[nt], 0, 0, 0);
        }
    }

    if (w > 0) {
        #pragma unroll
        for (int nt = 0; nt < 7; nt++)
            #pragma unroll
            for (int i = 0; i < 4; i++)
                red[w - 1][lane][nt * 4 + i] = acc[nt][i];
    }
    __syncthreads();
    if (w == 0) {
        #pragma unroll
        for (int nt = 0; nt < 7; nt++)
            #pragma unroll
            for (int i = 0; i < 4; i++)
                acc[nt][i] = ((acc[nt][i] + red[0][lane][nt * 4 + i])
                              + red[1][lane][nt * 4 + i]) + red[2][lane][nt * 4 + i];
        #pragma unroll
        for (int nt = 0; nt < 7; nt++) {
            int c = nt * 16 + m;
            if (c >= C_) continue;
            float bias = B2b[e * C_ + c];
            #pragma unroll
            for (int i = 0; i < 4; i++) {
                int grow = q * 4 + i;
                if (tile0 + grow < ce)
                    out[(size_t)rows[grow] * C_ + c] = acc[nt][i] + bias;
            }
        }
    }
}

// ---------------------------------------------------------------------------
extern "C" void kernel_launch(void* const* d_in, const int* in_sizes, int n_in,
                              void* d_out, int out_size, void* d_ws, size_t ws_size,
                              hipStream_t stream) {
    const float* x        = (const float*)d_in[0];
    const float* coeffs   = (const float*)d_in[1];
    const float* router_w = (const float*)d_in[2];
    const float* router_b = (const float*)d_in[3];
    const float* w1       = (const float*)d_in[4];
    const float* b1       = (const float*)d_in[5];
    const float* w2       = (const float*)d_in[6];
    const float* b2       = (const float*)d_in[7];
    float* out = (float*)d_out;

    // workspace layout: weight planes chunk-tiled (E*NCH*CHW ushorts each)
    unsigned short* Whi   = (unsigned short*)d_ws;        // E*96*10240 ush (15.7MB)
    unsigned short* Wlo   = Whi + (size_t)E_ * NCH_ * CHW_;
    unsigned short* W2thi = Wlo + (size_t)E_ * NCH_ * CHW_;  // E*C*H ush
    unsigned short* W2tlo = W2thi + (size_t)E_ * C_ * H_;
    float* B1b  = (float*)(W2tlo + (size_t)E_ * C_ * H_); // E*H
    float* B2b  = B1b + (size_t)E_ * H_;                  // E*C
    int* order  = (int*)(B2b + E_ * C_);                  // B (packed e<<16|b)
    int* cnt    = order + B_;                             // 8
    int* off    = cnt + E_;                               // 8
    int* tmap   = off + E_;                               // NTMAX
    int* tmap2  = tmap + NTMAX_;                          // NT2MAX
    int* ntl    = tmap2 + NT2MAX_;                        // 4
    int* idx    = ntl + 4;                                // B ints
    int* hist   = idx + B_;                               // RB*8 = 256 ints
    float* hws  = (float*)(hist + 256);                   // B*H f32 (slice 0)
    // lpart (RKS*B*8 f64 = 8 MB) aliases hws slice 0 exactly; dead before
    // gemm1 (use_part) / before the hws memset (fallback).
    double* lpart = (double*)hws;

    size_t prefix_bytes = (size_t)((char*)hws - (char*)d_ws);
    int use_part = (ws_size >= prefix_bytes + (size_t)KS_ * B_ * H_ * sizeof(float) + 256) ? 1 : 0;

    // one fused launch: router + W1/W2 blends + b1/b2 blends (overlapped)
    mega_k<<<dim3(MEGA_TOT_), 256, 0, stream>>>(
        x, router_w, w1, w2, b1, b2, Whi, Wlo, W2thi, W2tlo, B1b, B2b,
        lpart, coeffs);

    argmax_hist_k<<<dim3(RB_), 256, 0, stream>>>(lpart, router_b, coeffs, idx, hist);
    scatter2_k<<<dim3(RB_), 256, 0, stream>>>(idx, hist, order, cnt, off,
                                              tmap, tmap2, ntl);

    if (use_part) {
        // no memset needed: every (s,p,h) partial is written by exactly one block
        gemm1_t<1><<<dim3(KS_, NTMAX_), 256, 0, stream>>>(x, Whi, Wlo, order, cnt,
                                                          off, tmap, ntl, hws);
        // fused: slice-reduce + b1 + GELU inside gemm2's A-staging
        gemm2_t<1><<<dim3(NT2MAX_), 256, 0, stream>>>(hws, W2thi, W2tlo, B1b, B2b,
                                                      order, cnt, off, tmap2, ntl, out);
    } else {
        // zero hws (lpart alias dead), atomic partial sums
        hipMemsetAsync(hws, 0, (size_t)B_ * H_ * sizeof(float), stream);
        gemm1_t<0><<<dim3(KS_, NTMAX_), 256, 0, stream>>>(x, Whi, Wlo, order, cnt,
                                                          off, tmap, ntl, hws);
        bias_gelu_k<<<dim3(B_ * H_ / 4 / 256), 256, 0, stream>>>(hws, B1b, order);
        gemm2_t<0><<<dim3(NT2MAX_), 256, 0, stream>>>(hws, W2thi, W2tlo, B1b, B2b,
                                                      order, cnt, off, tmap2, ntl, out);
    }
}